// Round 3
// baseline (328.798 us; speedup 1.0000x reference)
//
#include <hip/hip_runtime.h>

// ---------------- problem constants ----------------
#define TDIM 48
#define DDIM 32
#define KDIM 1536      // T*D
#define HDIM 1024
#define GHID 128

typedef unsigned short u16;
typedef __bf16 bf16x8 __attribute__((ext_vector_type(8)));
typedef float  f32x4  __attribute__((ext_vector_type(4)));
typedef float  f32x16 __attribute__((ext_vector_type(16)));

typedef const void __attribute__((address_space(1))) gvoid;
typedef void       __attribute__((address_space(3))) lvoid;

__device__ __forceinline__ void gld_lds16(const void* g, void* l) {
    __builtin_amdgcn_global_load_lds((gvoid*)g, (lvoid*)l, 16, 0, 0);
}

__device__ __forceinline__ u16 f2bf(float f) {
    union { float f; unsigned u; } v; v.f = f;
    return (u16)((v.u + 0x7fffu + ((v.u >> 16) & 1u)) >> 16);
}

// ---------------- gate: fp64 MLP + bf16 cast of x ----------------
// 4 waves/block, one sample per wave. Also zero-inits out[0..2B) and cnt.
__global__ __launch_bounds__(256) void gate_kernel(
    const float* __restrict__ x,
    const float* __restrict__ gW1, const float* __restrict__ gb1,
    const float* __restrict__ gW2, const float* __restrict__ gb2,
    u16* __restrict__ Xbf, int* __restrict__ route, int* __restrict__ cnt,
    float* __restrict__ out, float* __restrict__ outDec, float* __restrict__ outProb)
{
    const int wave = threadIdx.x >> 6;
    const int lane = threadIdx.x & 63;
    const int b    = blockIdx.x * 4 + wave;
    if (blockIdx.x == 0 && threadIdx.x < 2) cnt[threadIdx.x] = 0;

    const float* xr = x + (size_t)b * KDIM;
    u16* xo = Xbf + (size_t)b * KDIM;

    double a0 = 0, a1 = 0, a2 = 0, a3 = 0;
#pragma unroll
    for (int i = 0; i < 6; ++i) {
        const int idx = i * 256 + lane * 4;
        float4 v = *(const float4*)(xr + idx);
        ushort4 o;
        o.x = f2bf(v.x); o.y = f2bf(v.y); o.z = f2bf(v.z); o.w = f2bf(v.w);
        *(ushort4*)(xo + idx) = o;
        a0 += v.x; a1 += v.y; a2 += v.z; a3 += v.w;
    }
    // lanes {l, l+8, ...} share columns 4*(l&7)..+3 -> reduce over bits 3,4,5
#pragma unroll
    for (int m = 8; m <= 32; m <<= 1) {
        a0 += __shfl_xor(a0, m); a1 += __shfl_xor(a1, m);
        a2 += __shfl_xor(a2, m); a3 += __shfl_xor(a3, m);
    }
    __shared__ double xm[4][DDIM];
    if (lane < 8) {
        xm[wave][4 * lane + 0] = a0 / 48.0; xm[wave][4 * lane + 1] = a1 / 48.0;
        xm[wave][4 * lane + 2] = a2 / 48.0; xm[wave][4 * lane + 3] = a3 / 48.0;
    }
    __builtin_amdgcn_wave_barrier();
    __builtin_amdgcn_s_waitcnt(0);   // lgkmcnt(0): LDS writes visible within wave
    __threadfence_block();

    // hidden: lane handles j = lane and lane+64
    double h0 = (double)gb1[lane], h1 = (double)gb1[lane + 64];
#pragma unroll
    for (int d = 0; d < DDIM; ++d) {
        const double xv = xm[wave][d];
        h0 += xv * (double)gW1[d * GHID + lane];
        h1 += xv * (double)gW1[d * GHID + 64 + lane];
    }
    h0 = h0 > 0.0 ? h0 : 0.0;
    h1 = h1 > 0.0 ? h1 : 0.0;
    double z0 = h0 * (double)gW2[lane * 2 + 0] + h1 * (double)gW2[(lane + 64) * 2 + 0];
    double z1 = h0 * (double)gW2[lane * 2 + 1] + h1 * (double)gW2[(lane + 64) * 2 + 1];
#pragma unroll
    for (int m = 1; m <= 32; m <<= 1) {
        z0 += __shfl_xor(z0, m);
        z1 += __shfl_xor(z1, m);
    }
    if (lane == 0) {
        z0 += (double)gb2[0]; z1 += (double)gb2[1];
        const int dec = (z1 > z0) ? 1 : 0;      // argmax, ties -> 0
        const double mz = z0 > z1 ? z0 : z1;
        const double e0 = exp(z0 - mz), e1 = exp(z1 - mz);
        const double p = (e0 > e1 ? e0 : e1) / (e0 + e1);
        const float pf = (float)p;               // stored prob is f32
        outDec[b]  = (float)dec;
        outProb[b] = pf;
        out[2 * b + 0] = 0.f;                    // zero-init for gemm atomics
        out[2 * b + 1] = 0.f;
        const int high = ((double)pf >= 0.7) ? 1 : 0;
        route[b] = (high && dec) ? 1 : 0;
    }
}

// ---------------- W1 transpose+cast: [1536,1024] f32 -> [1024,1536] bf16 ----
__global__ __launch_bounds__(256) void transpose_cast(
    const float* __restrict__ nW1, const float* __restrict__ aW1,
    u16* __restrict__ W1t)
{
    __shared__ float tile[32][33];
    const int e  = blockIdx.z;
    const float* W = e ? aW1 : nW1;
    u16* Wt = W1t + (size_t)e * HDIM * KDIM;
    const int bx = blockIdx.x;          // n-tile (1024/32)
    const int by = blockIdx.y;          // k-tile (1536/32)
    const int tx = threadIdx.x;         // 0..31
    const int ty = threadIdx.y;         // 0..7
#pragma unroll
    for (int r = 0; r < 32; r += 8)
        tile[ty + r][tx] = W[(size_t)(by * 32 + ty + r) * HDIM + bx * 32 + tx];
    __syncthreads();
#pragma unroll
    for (int r = 0; r < 32; r += 8)
        Wt[(size_t)(bx * 32 + ty + r) * KDIM + by * 32 + tx] = f2bf(tile[tx][ty + r]);
}

// ---------------- compaction: per-expert index lists -------------------------
__global__ __launch_bounds__(256) void compact_kernel(
    const int* __restrict__ route, int* __restrict__ perm, int* __restrict__ cnt,
    int Bn)
{
    const int b    = blockIdx.x * 256 + threadIdx.x;
    const int lane = threadIdx.x & 63;
    const int active = (b < Bn);
    const int e = active ? route[b] : 0;
    const unsigned long long m1 = __ballot(active && e == 1);
    const unsigned long long m0 = __ballot(active && e == 0);
    const unsigned long long below = (lane == 63) ? ~0ull >> 1 : ((1ull << lane) - 1);
    int base0 = 0, base1 = 0;
    if (lane == 0) {
        if (m0) base0 = atomicAdd(&cnt[0], (int)__popcll(m0));
        if (m1) base1 = atomicAdd(&cnt[1], (int)__popcll(m1));
    }
    base0 = __shfl(base0, 0);
    base1 = __shfl(base1, 0);
    if (active) {
        const int pos = e ? base1 + (int)__popcll(m1 & below)
                          : base0 + (int)__popcll(m0 & below);
        perm[e * Bn + pos] = b;
    }
}

// ---------------- expert GEMM: 128x128 tile, BK=64, 32x32x16 bf16 MFMA ------
// LDS layout [kgroup][row][8]: slot s = tid + 256*j maps linearly to LDS
// (glds constraint), g = s>>7, row = s&127 -> fragment reads are 16B-stride
// over rows (4-way bank alias only). XCD swizzle: 8 N-siblings share f%8.
__global__ __launch_bounds__(256, 4) void expert_gemm(
    const u16* __restrict__ Xbf, const u16* __restrict__ W1t,
    const float* __restrict__ nb1, const float* __restrict__ nW2,
    const float* __restrict__ nb2,
    const float* __restrict__ ab1, const float* __restrict__ aW2,
    const float* __restrict__ ab2,
    const int* __restrict__ perm, const int* __restrict__ cnt,
    float* __restrict__ out, int Bn, int mBlocks)
{
    __shared__ __align__(16) u16 Alds[8][128][8];   // 16 KB
    __shared__ __align__(16) u16 Blds[8][128][8];   // 16 KB
    __shared__ int   permLds[128];
    __shared__ float w2Lds[128 * 2];
    __shared__ float b1Lds[128];

    const int tid = threadIdx.x;
    // swizzle: f = g*64 + n*8 + mlow  ->  m = g*8 + mlow, XCD(f)=f%8=mlow
    const int f    = (int)blockIdx.x;
    const int g4   = f >> 6;
    const int nIdx = (f >> 3) & 7;
    const int mGlb = g4 * 8 + (f & 7);
    const int e  = mGlb >= mBlocks;
    const int mb = mGlb - (e ? mBlocks : 0);
    const int cntE = cnt[e];
    const int start = mb * 128;
    if (start >= cntE) return;
    const int valid = min(128, cntE - start);

    const int n0 = nIdx * 128;
    const u16*  W1e = W1t + (size_t)e * HDIM * KDIM;
    const float* b1 = e ? ab1 : nb1;
    const float* w2 = e ? aW2 : nW2;
    const float* b2 = e ? ab2 : nb2;

    if (tid < 128) permLds[tid] = perm[e * Bn + min(start + tid, cntE - 1)];
    if (tid >= 128) {
        const int j = tid - 128;
        b1Lds[j]        = b1[n0 + j];
        w2Lds[j * 2 + 0] = w2[(n0 + j) * 2 + 0];
        w2Lds[j * 2 + 1] = w2[(n0 + j) * 2 + 1];
    }
    __syncthreads();

    // staging: slot s = tid + 256*j covers kgroup g = s>>7, row = s&127.
    // g = 2*j + (tid>>7) -> global element offset = (tid>>7)*8 + j*16.
    const int rowS  = tid & 127;
    const int gBase = tid >> 7;
    const u16* gA = Xbf + (size_t)permLds[rowS] * KDIM + gBase * 8;
    const u16* gB = W1e + (size_t)(n0 + rowS) * KDIM + gBase * 8;
    u16* la = (u16*)Alds + tid * 8;
    u16* lb = (u16*)Blds + tid * 8;

    const int wave = tid >> 6;
    const int lane = tid & 63;
    const int wm   = (wave & 1) * 64;
    const int wn   = (wave >> 1) * 64;
    const int l31  = lane & 31;
    const int khalf = lane >> 5;

    f32x16 acc00 = (f32x16)0.f, acc01 = (f32x16)0.f;
    f32x16 acc10 = (f32x16)0.f, acc11 = (f32x16)0.f;

    for (int k0 = 0; k0 < KDIM; k0 += 64) {
#pragma unroll
        for (int j = 0; j < 4; ++j)
            gld_lds16(gA + k0 + j * 16, la + j * 2048);
#pragma unroll
        for (int j = 0; j < 4; ++j)
            gld_lds16(gB + k0 + j * 16, lb + j * 2048);
        __syncthreads();   // drains vmcnt(0): LDS tiles ready

#pragma unroll
        for (int t = 0; t < 4; ++t) {
            const int g = 2 * t + khalf;
            bf16x8 af0 = *reinterpret_cast<const bf16x8*>(&Alds[g][wm + l31][0]);
            bf16x8 af1 = *reinterpret_cast<const bf16x8*>(&Alds[g][wm + 32 + l31][0]);
            bf16x8 bv0 = *reinterpret_cast<const bf16x8*>(&Blds[g][wn + l31][0]);
            bf16x8 bv1 = *reinterpret_cast<const bf16x8*>(&Blds[g][wn + 32 + l31][0]);
            acc00 = __builtin_amdgcn_mfma_f32_32x32x16_bf16(af0, bv0, acc00, 0, 0, 0);
            acc01 = __builtin_amdgcn_mfma_f32_32x32x16_bf16(af0, bv1, acc01, 0, 0, 0);
            acc10 = __builtin_amdgcn_mfma_f32_32x32x16_bf16(af1, bv0, acc10, 0, 0, 0);
            acc11 = __builtin_amdgcn_mfma_f32_32x32x16_bf16(af1, bv1, acc11, 0, 0, 0);
        }
        __syncthreads();   // all waves done reading before next overwrite
    }

    // epilogue: h = relu(acc + b1); partial out = h @ W2[128x2]; atomic add.
    // 32x32 C/D layout: col = lane&31, row = (reg&3) + 8*(reg>>2) + 4*(lane>>5)
    const float b2_0 = (n0 == 0) ? b2[0] : 0.f;
    const float b2_1 = (n0 == 0) ? b2[1] : 0.f;
#pragma unroll
    for (int mi = 0; mi < 2; ++mi) {
        float p0[16], p1[16];
#pragma unroll
        for (int r = 0; r < 16; ++r) { p0[r] = 0.f; p1[r] = 0.f; }
#pragma unroll
        for (int ni = 0; ni < 2; ++ni) {
            const f32x16 a = (mi == 0) ? (ni == 0 ? acc00 : acc01)
                                       : (ni == 0 ? acc10 : acc11);
            const int col = wn + ni * 32 + l31;
            const float w20 = w2Lds[col * 2 + 0];
            const float w21 = w2Lds[col * 2 + 1];
            const float bb  = b1Lds[col];
#pragma unroll
            for (int r = 0; r < 16; ++r) {
                float h = a[r] + bb;
                h = fmaxf(h, 0.f);
                p0[r] += h * w20;
                p1[r] += h * w21;
            }
        }
#pragma unroll
        for (int m = 1; m <= 16; m <<= 1) {
#pragma unroll
            for (int r = 0; r < 16; ++r) {
                p0[r] += __shfl_xor(p0[r], m);
                p1[r] += __shfl_xor(p1[r], m);
            }
        }
        if (l31 == 0) {
#pragma unroll
            for (int r = 0; r < 16; ++r) {
                const int lrow = wm + mi * 32 + (r & 3) + 8 * (r >> 2) + 4 * khalf;
                if (lrow < valid) {
                    const int srow = permLds[lrow];
                    atomicAdd(&out[srow * 2 + 0], p0[r] + b2_0);
                    atomicAdd(&out[srow * 2 + 1], p1[r] + b2_1);
                }
            }
        }
    }
}

// ---------------- launch ----------------
extern "C" void kernel_launch(void* const* d_in, const int* in_sizes, int n_in,
                              void* d_out, int out_size, void* d_ws, size_t ws_size,
                              hipStream_t stream) {
    const float* x   = (const float*)d_in[0];
    const float* gW1 = (const float*)d_in[1];
    const float* gb1 = (const float*)d_in[2];
    const float* gW2 = (const float*)d_in[3];
    const float* gb2 = (const float*)d_in[4];
    const float* nW1 = (const float*)d_in[5];
    const float* nb1 = (const float*)d_in[6];
    const float* nW2 = (const float*)d_in[7];
    const float* nb2 = (const float*)d_in[8];
    const float* aW1 = (const float*)d_in[9];
    const float* ab1 = (const float*)d_in[10];
    const float* aW2 = (const float*)d_in[11];
    const float* ab2 = (const float*)d_in[12];

    float* out = (float*)d_out;
    const int Bn = in_sizes[0] / KDIM;           // 16384

    // workspace layout
    char* ws = (char*)d_ws;
    size_t off = 0;
    u16* Xbf = (u16*)(ws + off); off += (size_t)Bn * KDIM * sizeof(u16);           // 50.3 MB
    u16* W1t = (u16*)(ws + off); off += (size_t)2 * HDIM * KDIM * sizeof(u16);     // 6.3 MB
    int* perm = (int*)(ws + off); off += (size_t)2 * Bn * sizeof(int);             // 128 KB
    int* cnt  = (int*)(ws + off); off += 2 * sizeof(int);
    int* route = (int*)(ws + off); off += (size_t)Bn * sizeof(int);

    gate_kernel<<<Bn / 4, 256, 0, stream>>>(x, gW1, gb1, gW2, gb2,
                                            Xbf, route, cnt,
                                            out, out + 2 * Bn, out + 3 * Bn);

    transpose_cast<<<dim3(HDIM / 32, KDIM / 32, 2), dim3(32, 8), 0, stream>>>(nW1, aW1, W1t);

    compact_kernel<<<(Bn + 255) / 256, 256, 0, stream>>>(route, perm, cnt, Bn);

    const int mBlocks = (Bn + 127) / 128;        // 128
    expert_gemm<<<8 * 2 * mBlocks, 256, 0, stream>>>(
        Xbf, W1t, nb1, nW2, nb2, ab1, aW2, ab2, perm, cnt, out, Bn, mBlocks);
}

// Round 4
// 247.644 us; speedup vs baseline: 1.3277x; 1.3277x over previous
//
#include <hip/hip_runtime.h>

// ---------------- problem constants ----------------
#define TDIM 48
#define DDIM 32
#define KDIM 1536      // T*D
#define HDIM 1024
#define GHID 128

typedef unsigned short u16;
typedef __bf16 bf16x8 __attribute__((ext_vector_type(8)));
typedef float  f32x4  __attribute__((ext_vector_type(4)));

typedef const void __attribute__((address_space(1))) gvoid;
typedef void       __attribute__((address_space(3))) lvoid;

__device__ __forceinline__ void gld_lds16(const void* g, void* l) {
    __builtin_amdgcn_global_load_lds((gvoid*)g, (lvoid*)l, 16, 0, 0);
}

__device__ __forceinline__ u16 f2bf(float f) {
    union { float f; unsigned u; } v; v.f = f;
    return (u16)((v.u + 0x7fffu + ((v.u >> 16) & 1u)) >> 16);
}

// ---------------- gate: fp64 MLP + bf16 cast of x ----------------
// 4 waves/block, one sample per wave. Also zero-inits out[0..2B) and cnt.
__global__ __launch_bounds__(256) void gate_kernel(
    const float* __restrict__ x,
    const float* __restrict__ gW1, const float* __restrict__ gb1,
    const float* __restrict__ gW2, const float* __restrict__ gb2,
    u16* __restrict__ Xbf, int* __restrict__ route, int* __restrict__ cnt,
    float* __restrict__ out, float* __restrict__ outDec, float* __restrict__ outProb)
{
    const int wave = threadIdx.x >> 6;
    const int lane = threadIdx.x & 63;
    const int b    = blockIdx.x * 4 + wave;
    if (blockIdx.x == 0 && threadIdx.x < 2) cnt[threadIdx.x] = 0;

    const float* xr = x + (size_t)b * KDIM;
    u16* xo = Xbf + (size_t)b * KDIM;

    double a0 = 0, a1 = 0, a2 = 0, a3 = 0;
#pragma unroll
    for (int i = 0; i < 6; ++i) {
        const int idx = i * 256 + lane * 4;
        float4 v = *(const float4*)(xr + idx);
        ushort4 o;
        o.x = f2bf(v.x); o.y = f2bf(v.y); o.z = f2bf(v.z); o.w = f2bf(v.w);
        *(ushort4*)(xo + idx) = o;
        a0 += v.x; a1 += v.y; a2 += v.z; a3 += v.w;
    }
    // lanes {l, l+8, ...} share columns 4*(l&7)..+3 -> reduce over bits 3,4,5
#pragma unroll
    for (int m = 8; m <= 32; m <<= 1) {
        a0 += __shfl_xor(a0, m); a1 += __shfl_xor(a1, m);
        a2 += __shfl_xor(a2, m); a3 += __shfl_xor(a3, m);
    }
    __shared__ double xm[4][DDIM];
    if (lane < 8) {
        xm[wave][4 * lane + 0] = a0 / 48.0; xm[wave][4 * lane + 1] = a1 / 48.0;
        xm[wave][4 * lane + 2] = a2 / 48.0; xm[wave][4 * lane + 3] = a3 / 48.0;
    }
    __builtin_amdgcn_wave_barrier();
    __builtin_amdgcn_s_waitcnt(0);   // lgkmcnt(0): LDS writes visible within wave
    __threadfence_block();

    // hidden: lane handles j = lane and lane+64
    double h0 = (double)gb1[lane], h1 = (double)gb1[lane + 64];
#pragma unroll
    for (int d = 0; d < DDIM; ++d) {
        const double xv = xm[wave][d];
        h0 += xv * (double)gW1[d * GHID + lane];
        h1 += xv * (double)gW1[d * GHID + 64 + lane];
    }
    h0 = h0 > 0.0 ? h0 : 0.0;
    h1 = h1 > 0.0 ? h1 : 0.0;
    double z0 = h0 * (double)gW2[lane * 2 + 0] + h1 * (double)gW2[(lane + 64) * 2 + 0];
    double z1 = h0 * (double)gW2[lane * 2 + 1] + h1 * (double)gW2[(lane + 64) * 2 + 1];
#pragma unroll
    for (int m = 1; m <= 32; m <<= 1) {
        z0 += __shfl_xor(z0, m);
        z1 += __shfl_xor(z1, m);
    }
    if (lane == 0) {
        z0 += (double)gb2[0]; z1 += (double)gb2[1];
        const int dec = (z1 > z0) ? 1 : 0;      // argmax, ties -> 0
        const double mz = z0 > z1 ? z0 : z1;
        const double e0 = exp(z0 - mz), e1 = exp(z1 - mz);
        const double p = (e0 > e1 ? e0 : e1) / (e0 + e1);
        const float pf = (float)p;               // stored prob is f32
        outDec[b]  = (float)dec;
        outProb[b] = pf;
        out[2 * b + 0] = 0.f;                    // zero-init for gemm atomics
        out[2 * b + 1] = 0.f;
        const int high = ((double)pf >= 0.7) ? 1 : 0;
        route[b] = (high && dec) ? 1 : 0;
    }
}

// ---------------- W1 transpose+cast: [1536,1024] f32 -> [1024,1536] bf16 ----
__global__ __launch_bounds__(256) void transpose_cast(
    const float* __restrict__ nW1, const float* __restrict__ aW1,
    u16* __restrict__ W1t)
{
    __shared__ float tile[32][33];
    const int e  = blockIdx.z;
    const float* W = e ? aW1 : nW1;
    u16* Wt = W1t + (size_t)e * HDIM * KDIM;
    const int bx = blockIdx.x;          // n-tile (1024/32)
    const int by = blockIdx.y;          // k-tile (1536/32)
    const int tx = threadIdx.x;         // 0..31
    const int ty = threadIdx.y;         // 0..7
#pragma unroll
    for (int r = 0; r < 32; r += 8)
        tile[ty + r][tx] = W[(size_t)(by * 32 + ty + r) * HDIM + bx * 32 + tx];
    __syncthreads();
#pragma unroll
    for (int r = 0; r < 32; r += 8)
        Wt[(size_t)(bx * 32 + ty + r) * KDIM + by * 32 + tx] = f2bf(tile[tx][ty + r]);
}

// ---------------- compaction: per-expert index lists -------------------------
__global__ __launch_bounds__(256) void compact_kernel(
    const int* __restrict__ route, int* __restrict__ perm, int* __restrict__ cnt,
    int Bn)
{
    const int b    = blockIdx.x * 256 + threadIdx.x;
    const int lane = threadIdx.x & 63;
    const int active = (b < Bn);
    const int e = active ? route[b] : 0;
    const unsigned long long m1 = __ballot(active && e == 1);
    const unsigned long long m0 = __ballot(active && e == 0);
    const unsigned long long below = (lane == 63) ? ~0ull >> 1 : ((1ull << lane) - 1);
    int base0 = 0, base1 = 0;
    if (lane == 0) {
        if (m0) base0 = atomicAdd(&cnt[0], (int)__popcll(m0));
        if (m1) base1 = atomicAdd(&cnt[1], (int)__popcll(m1));
    }
    base0 = __shfl(base0, 0);
    base1 = __shfl(base1, 0);
    if (active) {
        const int pos = e ? base1 + (int)__popcll(m1 & below)
                          : base0 + (int)__popcll(m0 & below);
        perm[e * Bn + pos] = b;
    }
}

// ---------------- expert GEMM: 128x128 tile, BK=64, 16x16x32 bf16 MFMA ------
// LDS layout [row][8 chunks x 16B], chunk c of row r stored at c^(r&7)
// (source-side swizzle: lane fetches global chunk cg=(tid&7)^((tid>>3)&7),
//  still within the same contiguous 128B row segment -> coalescing intact,
//  fragment reads spread over all 8 bank groups -> conflict-free).
// XCD swizzle: 8 N-siblings of an M-tile share flat%8.
__global__ __launch_bounds__(256, 2) void expert_gemm(
    const u16* __restrict__ Xbf, const u16* __restrict__ W1t,
    const float* __restrict__ nb1, const float* __restrict__ nW2,
    const float* __restrict__ nb2,
    const float* __restrict__ ab1, const float* __restrict__ aW2,
    const float* __restrict__ ab2,
    const int* __restrict__ perm, const int* __restrict__ cnt,
    float* __restrict__ out, int Bn, int mBlocks)
{
    __shared__ __align__(16) u16 Alds[128 * 64];   // 16 KB, [row][64k swizzled]
    __shared__ __align__(16) u16 Blds[128 * 64];   // 16 KB
    __shared__ int   permLds[128];
    __shared__ float w2Lds[128 * 2];
    __shared__ float b1Lds[128];

    const int tid = threadIdx.x;
    // swizzle: f = g*64 + n*8 + mlow  ->  m = g*8 + mlow, XCD(f)=f%8=mlow
    const int f    = (int)blockIdx.x;
    const int g4   = f >> 6;
    const int nIdx = (f >> 3) & 7;
    const int mGlb = g4 * 8 + (f & 7);
    const int e  = mGlb >= mBlocks;
    const int mb = mGlb - (e ? mBlocks : 0);
    const int cntE = cnt[e];
    const int start = mb * 128;
    if (start >= cntE) return;
    const int valid = min(128, cntE - start);

    const int n0 = nIdx * 128;
    const u16*  W1e = W1t + (size_t)e * HDIM * KDIM;
    const float* b1 = e ? ab1 : nb1;
    const float* w2 = e ? aW2 : nW2;
    const float* b2 = e ? ab2 : nb2;

    if (tid < 128) permLds[tid] = perm[e * Bn + min(start + tid, cntE - 1)];
    if (tid >= 128) {
        const int j = tid - 128;
        b1Lds[j]        = b1[n0 + j];
        w2Lds[j * 2 + 0] = w2[(n0 + j) * 2 + 0];
        w2Lds[j * 2 + 1] = w2[(n0 + j) * 2 + 1];
    }
    __syncthreads();

    // staging: slot s = tid + 256*j -> LDS row s>>3 = (tid>>3)+32j, pos tid&7.
    // That slot must hold tile chunk cg = (tid&7) ^ (row&7); row&7 == (tid>>3)&7.
    const int rbase = tid >> 3;
    const int cg    = (tid & 7) ^ (rbase & 7);
    const u16* gA[4]; const u16* gB[4];
#pragma unroll
    for (int j = 0; j < 4; ++j) {
        gA[j] = Xbf + (size_t)permLds[rbase + 32 * j] * KDIM + cg * 8;
        gB[j] = W1e + (size_t)(n0 + rbase + 32 * j) * KDIM + cg * 8;
    }
    u16* la = (u16*)Alds + tid * 8;
    u16* lb = (u16*)Blds + tid * 8;

    const int wave = tid >> 6;
    const int lane = tid & 63;
    const int wm   = (wave & 1) * 64;
    const int wn   = (wave >> 1) * 64;
    const int l15  = lane & 15;
    const int quad = lane >> 4;

    f32x4 acc[4][4];
#pragma unroll
    for (int i = 0; i < 4; ++i)
#pragma unroll
        for (int j = 0; j < 4; ++j) acc[i][j] = (f32x4)0.f;

    for (int k0 = 0; k0 < KDIM; k0 += 64) {
#pragma unroll
        for (int j = 0; j < 4; ++j)
            gld_lds16(gA[j] + k0, la + j * 2048);
#pragma unroll
        for (int j = 0; j < 4; ++j)
            gld_lds16(gB[j] + k0, lb + j * 2048);
        __syncthreads();   // drains vmcnt(0): LDS tiles ready

#pragma unroll
        for (int t = 0; t < 2; ++t) {
            bf16x8 af[4], bfv[4];
#pragma unroll
            for (int mi = 0; mi < 4; ++mi) {
                const int r = wm + mi * 16 + l15;
                const int p = (t * 4 + quad) ^ (r & 7);
                af[mi] = *reinterpret_cast<const bf16x8*>(&Alds[r * 64 + p * 8]);
            }
#pragma unroll
            for (int ni = 0; ni < 4; ++ni) {
                const int r = wn + ni * 16 + l15;
                const int p = (t * 4 + quad) ^ (r & 7);
                bfv[ni] = *reinterpret_cast<const bf16x8*>(&Blds[r * 64 + p * 8]);
            }
#pragma unroll
            for (int mi = 0; mi < 4; ++mi)
#pragma unroll
                for (int ni = 0; ni < 4; ++ni)
                    acc[mi][ni] = __builtin_amdgcn_mfma_f32_16x16x32_bf16(af[mi], bfv[ni], acc[mi][ni], 0, 0, 0);
        }
        __syncthreads();   // all waves done reading before next overwrite
    }

    // epilogue: h = relu(acc + b1); partial out = h @ W2[128x2]; atomic add
    const float b2_0 = (n0 == 0) ? b2[0] : 0.f;
    const float b2_1 = (n0 == 0) ? b2[1] : 0.f;
#pragma unroll
    for (int mi = 0; mi < 4; ++mi) {
        float p0[4] = {0.f, 0.f, 0.f, 0.f};
        float p1[4] = {0.f, 0.f, 0.f, 0.f};
#pragma unroll
        for (int ni = 0; ni < 4; ++ni) {
            const int col = wn + ni * 16 + l15;
            const float w20 = w2Lds[col * 2 + 0];
            const float w21 = w2Lds[col * 2 + 1];
            const float bb  = b1Lds[col];
#pragma unroll
            for (int r = 0; r < 4; ++r) {
                float h = acc[mi][ni][r] + bb;
                h = fmaxf(h, 0.f);
                p0[r] += h * w20;
                p1[r] += h * w21;
            }
        }
#pragma unroll
        for (int m = 1; m <= 8; m <<= 1) {
#pragma unroll
            for (int r = 0; r < 4; ++r) {
                p0[r] += __shfl_xor(p0[r], m);
                p1[r] += __shfl_xor(p1[r], m);
            }
        }
        if (l15 < 4) {
            const int r = l15;
            const int lrow = wm + mi * 16 + quad * 4 + r;
            if (lrow < valid) {
                const int srow = permLds[lrow];
                atomicAdd(&out[srow * 2 + 0], p0[r] + b2_0);
                atomicAdd(&out[srow * 2 + 1], p1[r] + b2_1);
            }
        }
    }
}

// ---------------- launch ----------------
extern "C" void kernel_launch(void* const* d_in, const int* in_sizes, int n_in,
                              void* d_out, int out_size, void* d_ws, size_t ws_size,
                              hipStream_t stream) {
    const float* x   = (const float*)d_in[0];
    const float* gW1 = (const float*)d_in[1];
    const float* gb1 = (const float*)d_in[2];
    const float* gW2 = (const float*)d_in[3];
    const float* gb2 = (const float*)d_in[4];
    const float* nW1 = (const float*)d_in[5];
    const float* nb1 = (const float*)d_in[6];
    const float* nW2 = (const float*)d_in[7];
    const float* nb2 = (const float*)d_in[8];
    const float* aW1 = (const float*)d_in[9];
    const float* ab1 = (const float*)d_in[10];
    const float* aW2 = (const float*)d_in[11];
    const float* ab2 = (const float*)d_in[12];

    float* out = (float*)d_out;
    const int Bn = in_sizes[0] / KDIM;           // 16384

    // workspace layout
    char* ws = (char*)d_ws;
    size_t off = 0;
    u16* Xbf = (u16*)(ws + off); off += (size_t)Bn * KDIM * sizeof(u16);           // 50.3 MB
    u16* W1t = (u16*)(ws + off); off += (size_t)2 * HDIM * KDIM * sizeof(u16);     // 6.3 MB
    int* perm = (int*)(ws + off); off += (size_t)2 * Bn * sizeof(int);             // 128 KB
    int* cnt  = (int*)(ws + off); off += 2 * sizeof(int);
    int* route = (int*)(ws + off); off += (size_t)Bn * sizeof(int);

    gate_kernel<<<Bn / 4, 256, 0, stream>>>(x, gW1, gb1, gW2, gb2,
                                            Xbf, route, cnt,
                                            out, out + 2 * Bn, out + 3 * Bn);

    transpose_cast<<<dim3(HDIM / 32, KDIM / 32, 2), dim3(32, 8), 0, stream>>>(nW1, aW1, W1t);

    compact_kernel<<<(Bn + 255) / 256, 256, 0, stream>>>(route, perm, cnt, Bn);

    const int mBlocks = (Bn + 127) / 128;        // 128
    expert_gemm<<<8 * 2 * mBlocks, 256, 0, stream>>>(
        Xbf, W1t, nb1, nW2, nb2, ab1, aW2, ab2, perm, cnt, out, Bn, mBlocks);
}

// Round 5
// 235.711 us; speedup vs baseline: 1.3949x; 1.0506x over previous
//
#include <hip/hip_runtime.h>

// ---------------- problem constants ----------------
#define TDIM 48
#define DDIM 32
#define KDIM 1536      // T*D
#define HDIM 1024
#define GHID 128

typedef unsigned short u16;
typedef __bf16 bf16x8 __attribute__((ext_vector_type(8)));
typedef float  f32x4  __attribute__((ext_vector_type(4)));

typedef const void __attribute__((address_space(1))) gvoid;
typedef void       __attribute__((address_space(3))) lvoid;

__device__ __forceinline__ void gld_lds16(const void* g, void* l) {
    __builtin_amdgcn_global_load_lds((gvoid*)g, (lvoid*)l, 16, 0, 0);
}

__device__ __forceinline__ u16 f2bf(float f) {
    union { float f; unsigned u; } v; v.f = f;
    return (u16)((v.u + 0x7fffu + ((v.u >> 16) & 1u)) >> 16);
}

// ---------------- gate: fp64 MLP + bf16 cast of x ----------------
// 4 waves/block, one sample per wave. Also zero-inits out[0..2B) and cnt.
// x is single-use -> nontemporal loads keep Xbf/W1t resident in L3 for gemm.
__global__ __launch_bounds__(256) void gate_kernel(
    const float* __restrict__ x,
    const float* __restrict__ gW1, const float* __restrict__ gb1,
    const float* __restrict__ gW2, const float* __restrict__ gb2,
    u16* __restrict__ Xbf, int* __restrict__ route, int* __restrict__ cnt,
    float* __restrict__ out, float* __restrict__ outDec, float* __restrict__ outProb)
{
    const int wave = threadIdx.x >> 6;
    const int lane = threadIdx.x & 63;
    const int b    = blockIdx.x * 4 + wave;
    if (blockIdx.x == 0 && threadIdx.x < 2) cnt[threadIdx.x] = 0;

    const float* xr = x + (size_t)b * KDIM;
    u16* xo = Xbf + (size_t)b * KDIM;

    double a0 = 0, a1 = 0, a2 = 0, a3 = 0;
#pragma unroll
    for (int i = 0; i < 6; ++i) {
        const int idx = i * 256 + lane * 4;
        f32x4 v = __builtin_nontemporal_load((const f32x4*)(xr + idx));
        ushort4 o;
        o.x = f2bf(v[0]); o.y = f2bf(v[1]); o.z = f2bf(v[2]); o.w = f2bf(v[3]);
        *(ushort4*)(xo + idx) = o;
        a0 += v[0]; a1 += v[1]; a2 += v[2]; a3 += v[3];
    }
    // lanes {l, l+8, ...} share columns 4*(l&7)..+3 -> reduce over bits 3,4,5
#pragma unroll
    for (int m = 8; m <= 32; m <<= 1) {
        a0 += __shfl_xor(a0, m); a1 += __shfl_xor(a1, m);
        a2 += __shfl_xor(a2, m); a3 += __shfl_xor(a3, m);
    }
    __shared__ double xm[4][DDIM];
    if (lane < 8) {
        xm[wave][4 * lane + 0] = a0 / 48.0; xm[wave][4 * lane + 1] = a1 / 48.0;
        xm[wave][4 * lane + 2] = a2 / 48.0; xm[wave][4 * lane + 3] = a3 / 48.0;
    }
    __builtin_amdgcn_wave_barrier();
    __builtin_amdgcn_s_waitcnt(0);   // lgkmcnt(0): LDS writes visible within wave
    __threadfence_block();

    // hidden: lane handles j = lane and lane+64
    double h0 = (double)gb1[lane], h1 = (double)gb1[lane + 64];
#pragma unroll
    for (int d = 0; d < DDIM; ++d) {
        const double xv = xm[wave][d];
        h0 += xv * (double)gW1[d * GHID + lane];
        h1 += xv * (double)gW1[d * GHID + 64 + lane];
    }
    h0 = h0 > 0.0 ? h0 : 0.0;
    h1 = h1 > 0.0 ? h1 : 0.0;
    double z0 = h0 * (double)gW2[lane * 2 + 0] + h1 * (double)gW2[(lane + 64) * 2 + 0];
    double z1 = h0 * (double)gW2[lane * 2 + 1] + h1 * (double)gW2[(lane + 64) * 2 + 1];
#pragma unroll
    for (int m = 1; m <= 32; m <<= 1) {
        z0 += __shfl_xor(z0, m);
        z1 += __shfl_xor(z1, m);
    }
    if (lane == 0) {
        z0 += (double)gb2[0]; z1 += (double)gb2[1];
        const int dec = (z1 > z0) ? 1 : 0;      // argmax, ties -> 0
        const double mz = z0 > z1 ? z0 : z1;
        const double e0 = exp(z0 - mz), e1 = exp(z1 - mz);
        const double p = (e0 > e1 ? e0 : e1) / (e0 + e1);
        const float pf = (float)p;               // stored prob is f32
        outDec[b]  = (float)dec;
        outProb[b] = pf;
        out[2 * b + 0] = 0.f;                    // zero-init for gemm atomics
        out[2 * b + 1] = 0.f;
        const int high = ((double)pf >= 0.7) ? 1 : 0;
        route[b] = (high && dec) ? 1 : 0;
    }
}

// ---------------- fused: compaction (blocks 0..63) + W1 transpose-cast ------
// compact: per-expert index lists from route[].
// transpose: [1536,1024] f32 -> [1024,1536] bf16, blocks 64..64+2*1536.
__global__ __launch_bounds__(256) void compact_transpose(
    const int* __restrict__ route, int* __restrict__ perm, int* __restrict__ cnt,
    int Bn,
    const float* __restrict__ nW1, const float* __restrict__ aW1,
    u16* __restrict__ W1t)
{
    __shared__ float tile[32][33];
    const int blk = (int)blockIdx.x;
    const int tid = threadIdx.x;

    if (blk < 64) {
        // ---- compact ----
        const int b    = blk * 256 + tid;
        const int lane = tid & 63;
        const int active = (b < Bn);
        const int e = active ? route[b] : 0;
        const unsigned long long m1 = __ballot(active && e == 1);
        const unsigned long long m0 = __ballot(active && e == 0);
        const unsigned long long below = (lane == 63) ? ~0ull >> 1 : ((1ull << lane) - 1);
        int base0 = 0, base1 = 0;
        if (lane == 0) {
            if (m0) base0 = atomicAdd(&cnt[0], (int)__popcll(m0));
            if (m1) base1 = atomicAdd(&cnt[1], (int)__popcll(m1));
        }
        base0 = __shfl(base0, 0);
        base1 = __shfl(base1, 0);
        if (active) {
            const int pos = e ? base1 + (int)__popcll(m1 & below)
                              : base0 + (int)__popcll(m0 & below);
            perm[e * Bn + pos] = b;
        }
    } else {
        // ---- transpose-cast ----
        int t = blk - 64;                       // 0..3071
        const int e = t >= (32 * 48);
        t -= e ? (32 * 48) : 0;
        const int bx = t & 31;                  // n-tile (1024/32)
        const int by = t >> 5;                  // k-tile (1536/32)
        const float* W = e ? aW1 : nW1;
        u16* Wt = W1t + (size_t)e * HDIM * KDIM;
        const int tx = tid & 31;                // 0..31
        const int ty = tid >> 5;                // 0..7
#pragma unroll
        for (int r = 0; r < 32; r += 8)
            tile[ty + r][tx] = W[(size_t)(by * 32 + ty + r) * HDIM + bx * 32 + tx];
        __syncthreads();
#pragma unroll
        for (int r = 0; r < 32; r += 8)
            Wt[(size_t)(bx * 32 + ty + r) * KDIM + by * 32 + tx] = f2bf(tile[tx][ty + r]);
    }
}

// ---------------- expert GEMM: 128x128 tile, BK=64, 16x16x32 bf16 MFMA ------
// LDS layout [row][8 chunks x 16B], chunk c of row r stored at c^(r&7)
// (source-side swizzle keeps glds coalescing intact; fragment reads spread
//  over all 8 bank groups -> conflict-free). XCD swizzle: 8 N-siblings of an
// M-tile share flat%8. launch_bounds (256,4): 64 VGPR + 64 AGPR = 128/wave
// -> 4 blocks/CU (LDS 34KB*4 = 139KB fits) for cross-block barrier overlap.
__global__ __launch_bounds__(256, 4) void expert_gemm(
    const u16* __restrict__ Xbf, const u16* __restrict__ W1t,
    const float* __restrict__ nb1, const float* __restrict__ nW2,
    const float* __restrict__ nb2,
    const float* __restrict__ ab1, const float* __restrict__ aW2,
    const float* __restrict__ ab2,
    const int* __restrict__ perm, const int* __restrict__ cnt,
    float* __restrict__ out, int Bn, int mBlocks)
{
    __shared__ __align__(16) u16 Alds[128 * 64];   // 16 KB, [row][64k swizzled]
    __shared__ __align__(16) u16 Blds[128 * 64];   // 16 KB
    __shared__ int   permLds[128];
    __shared__ float w2Lds[128 * 2];
    __shared__ float b1Lds[128];

    const int tid = threadIdx.x;
    // swizzle: f = g*64 + n*8 + mlow  ->  m = g*8 + mlow, XCD(f)=f%8=mlow
    const int f    = (int)blockIdx.x;
    const int g4   = f >> 6;
    const int nIdx = (f >> 3) & 7;
    const int mGlb = g4 * 8 + (f & 7);
    const int e  = mGlb >= mBlocks;
    const int mb = mGlb - (e ? mBlocks : 0);
    const int cntE = cnt[e];
    const int start = mb * 128;
    if (start >= cntE) return;
    const int valid = min(128, cntE - start);

    const int n0 = nIdx * 128;
    const u16*  W1e = W1t + (size_t)e * HDIM * KDIM;
    const float* b1 = e ? ab1 : nb1;
    const float* w2 = e ? aW2 : nW2;
    const float* b2 = e ? ab2 : nb2;

    if (tid < 128) permLds[tid] = perm[e * Bn + min(start + tid, cntE - 1)];
    if (tid >= 128) {
        const int j = tid - 128;
        b1Lds[j]        = b1[n0 + j];
        w2Lds[j * 2 + 0] = w2[(n0 + j) * 2 + 0];
        w2Lds[j * 2 + 1] = w2[(n0 + j) * 2 + 1];
    }
    __syncthreads();

    // staging: slot s = tid + 256*j -> LDS row s>>3 = (tid>>3)+32j, pos tid&7.
    // That slot must hold tile chunk cg = (tid&7) ^ (row&7); row&7 == (tid>>3)&7.
    const int rbase = tid >> 3;
    const int cg    = (tid & 7) ^ (rbase & 7);
    const u16* gA[4]; const u16* gB[4];
#pragma unroll
    for (int j = 0; j < 4; ++j) {
        gA[j] = Xbf + (size_t)permLds[rbase + 32 * j] * KDIM + cg * 8;
        gB[j] = W1e + (size_t)(n0 + rbase + 32 * j) * KDIM + cg * 8;
    }
    u16* la = (u16*)Alds + tid * 8;
    u16* lb = (u16*)Blds + tid * 8;

    const int wave = tid >> 6;
    const int lane = tid & 63;
    const int wm   = (wave & 1) * 64;
    const int wn   = (wave >> 1) * 64;
    const int l15  = lane & 15;
    const int quad = lane >> 4;

    f32x4 acc[4][4];
#pragma unroll
    for (int i = 0; i < 4; ++i)
#pragma unroll
        for (int j = 0; j < 4; ++j) acc[i][j] = (f32x4)0.f;

    for (int k0 = 0; k0 < KDIM; k0 += 64) {
#pragma unroll
        for (int j = 0; j < 4; ++j)
            gld_lds16(gA[j] + k0, la + j * 2048);
#pragma unroll
        for (int j = 0; j < 4; ++j)
            gld_lds16(gB[j] + k0, lb + j * 2048);
        __syncthreads();   // drains vmcnt(0): LDS tiles ready

#pragma unroll
        for (int t = 0; t < 2; ++t) {
            bf16x8 af[4], bfv[4];
#pragma unroll
            for (int mi = 0; mi < 4; ++mi) {
                const int r = wm + mi * 16 + l15;
                const int p = (t * 4 + quad) ^ (r & 7);
                af[mi] = *reinterpret_cast<const bf16x8*>(&Alds[r * 64 + p * 8]);
            }
#pragma unroll
            for (int ni = 0; ni < 4; ++ni) {
                const int r = wn + ni * 16 + l15;
                const int p = (t * 4 + quad) ^ (r & 7);
                bfv[ni] = *reinterpret_cast<const bf16x8*>(&Blds[r * 64 + p * 8]);
            }
#pragma unroll
            for (int mi = 0; mi < 4; ++mi)
#pragma unroll
                for (int ni = 0; ni < 4; ++ni)
                    acc[mi][ni] = __builtin_amdgcn_mfma_f32_16x16x32_bf16(af[mi], bfv[ni], acc[mi][ni], 0, 0, 0);
        }
        __syncthreads();   // all waves done reading before next overwrite
    }

    // epilogue: h = relu(acc + b1); partial out = h @ W2[128x2]; atomic add
    const float b2_0 = (n0 == 0) ? b2[0] : 0.f;
    const float b2_1 = (n0 == 0) ? b2[1] : 0.f;
#pragma unroll
    for (int mi = 0; mi < 4; ++mi) {
        float p0[4] = {0.f, 0.f, 0.f, 0.f};
        float p1[4] = {0.f, 0.f, 0.f, 0.f};
#pragma unroll
        for (int ni = 0; ni < 4; ++ni) {
            const int col = wn + ni * 16 + l15;
            const float w20 = w2Lds[col * 2 + 0];
            const float w21 = w2Lds[col * 2 + 1];
            const float bb  = b1Lds[col];
#pragma unroll
            for (int r = 0; r < 4; ++r) {
                float h = acc[mi][ni][r] + bb;
                h = fmaxf(h, 0.f);
                p0[r] += h * w20;
                p1[r] += h * w21;
            }
        }
#pragma unroll
        for (int m = 1; m <= 8; m <<= 1) {
#pragma unroll
            for (int r = 0; r < 4; ++r) {
                p0[r] += __shfl_xor(p0[r], m);
                p1[r] += __shfl_xor(p1[r], m);
            }
        }
        if (l15 < 4) {
            const int r = l15;
            const int lrow = wm + mi * 16 + quad * 4 + r;
            if (lrow < valid) {
                const int srow = permLds[lrow];
                atomicAdd(&out[srow * 2 + 0], p0[r] + b2_0);
                atomicAdd(&out[srow * 2 + 1], p1[r] + b2_1);
            }
        }
    }
}

// ---------------- launch ----------------
extern "C" void kernel_launch(void* const* d_in, const int* in_sizes, int n_in,
                              void* d_out, int out_size, void* d_ws, size_t ws_size,
                              hipStream_t stream) {
    const float* x   = (const float*)d_in[0];
    const float* gW1 = (const float*)d_in[1];
    const float* gb1 = (const float*)d_in[2];
    const float* gW2 = (const float*)d_in[3];
    const float* gb2 = (const float*)d_in[4];
    const float* nW1 = (const float*)d_in[5];
    const float* nb1 = (const float*)d_in[6];
    const float* nW2 = (const float*)d_in[7];
    const float* nb2 = (const float*)d_in[8];
    const float* aW1 = (const float*)d_in[9];
    const float* ab1 = (const float*)d_in[10];
    const float* aW2 = (const float*)d_in[11];
    const float* ab2 = (const float*)d_in[12];

    float* out = (float*)d_out;
    const int Bn = in_sizes[0] / KDIM;           // 16384

    // workspace layout
    char* ws = (char*)d_ws;
    size_t off = 0;
    u16* Xbf = (u16*)(ws + off); off += (size_t)Bn * KDIM * sizeof(u16);           // 50.3 MB
    u16* W1t = (u16*)(ws + off); off += (size_t)2 * HDIM * KDIM * sizeof(u16);     // 6.3 MB
    int* perm = (int*)(ws + off); off += (size_t)2 * Bn * sizeof(int);             // 128 KB
    int* cnt  = (int*)(ws + off); off += 2 * sizeof(int);
    int* route = (int*)(ws + off); off += (size_t)Bn * sizeof(int);

    gate_kernel<<<Bn / 4, 256, 0, stream>>>(x, gW1, gb1, gW2, gb2,
                                            Xbf, route, cnt,
                                            out, out + 2 * Bn, out + 3 * Bn);

    compact_transpose<<<64 + 2 * (HDIM / 32) * (KDIM / 32), 256, 0, stream>>>(
        route, perm, cnt, Bn, nW1, aW1, W1t);

    const int mBlocks = (Bn + 127) / 128;        // 128
    expert_gemm<<<8 * 2 * mBlocks, 256, 0, stream>>>(
        Xbf, W1t, nb1, nW2, nb2, ab1, aW2, ab2, perm, cnt, out, Bn, mBlocks);
}